// Round 11
// baseline (78.858 us; speedup 1.0000x reference)
//
#include <hip/hip_runtime.h>
#include <stdint.h>

// SpikingKWTA analytical collapse (verified R1/R2/R6/R7, absmax 0.0):
//   potentials stay exactly 0.0f after every step => spk == bincount(ids),
//   final pot == 0 => values = spk*1e6; lax.top_k tie-break = lowest index.
//   Key (count<<32)|(0xFFFFFFFF - v): max-order == (count desc, index asc).
//   gains[v] = count ? 0.6 : 1.0; gains[top5] = 1.5. L>=1 => fallback dead.
//
// R11 = R8/R9/R10 resubmit (acquisition timeouts; never ran). Two dispatches,
// stream-ordered (R1 proved cross-dispatch order is free, ~0.25us;
// R2 proved per-wave agent fences cost 43us -- so split, don't fence).
//   K1 (1 block): LDS u64-slot hash histogram + block top-5. Writes 5 winner
//      indices to ws and gains[winner]=1.5. No V-wide work.
//   K2 (256 blocks x 512 thr): per-512-slice direct-mapped LDS flags (plain
//      racing stores of 1 -- no atomics), scan 16KB id list, write 0.6/1.0
//      for non-winners. All 256 CUs, ~2KB LDS, no inter-block comms.

typedef unsigned long long u64;

#define K_WIN 5
#define TB1 1024
#define HSZ 8192
#define HMASK (HSZ - 1)
#define TB2 512
#define SLICE2 512

static __device__ __forceinline__ uint32_t hashf(uint32_t x) {
    return (x * 2654435761u) >> 19;  // top 13 bits of Knuth mix
}
static __device__ __forceinline__ u64 u64max(u64 a, u64 b) { return a > b ? a : b; }

__global__ __launch_bounds__(TB1) void topk_kernel(const int* __restrict__ ids,
                                                   float* __restrict__ gains,
                                                   uint32_t* __restrict__ wsw,
                                                   int L, int V) {
    __shared__ u64 slot[HSZ];          // (count<<32) | (id+1); 0 = empty
    __shared__ u64 sWave[TB1 / 64];
    __shared__ u64 sWin;
    __shared__ uint32_t sWinners[K_WIN];   // winner INDICES (0xFFFFFFFF = none)

    const int tid = threadIdx.x;
    const int lane = tid & 63, wid = tid >> 6;

    for (int i = tid; i < HSZ; i += TB1) slot[i] = 0ull;
    __syncthreads();

    // --- Phase A: histogram into LDS hash ---
    for (int i0 = tid * 4; i0 < L; i0 += TB1 * 4) {
        int idv[4];
        int n = 0;
        if (i0 + 3 < L) {
            int4 w = *reinterpret_cast<const int4*>(ids + i0);
            idv[0] = w.x; idv[1] = w.y; idv[2] = w.z; idv[3] = w.w;
            n = 4;
        } else {
            for (; i0 + n < L && n < 4; ++n) idv[n] = ids[i0 + n];
        }
        for (int j = 0; j < n; ++j) {
            uint32_t id = (uint32_t)idv[j];
            uint32_t s = hashf(id) & HMASK;
            for (;;) {
                u64 cur = slot[s];
                uint32_t lo = (uint32_t)cur;
                if (lo == id + 1u) { atomicAdd(&slot[s], 1ull << 32); break; }
                if (lo == 0u) {
                    u64 got = atomicCAS(&slot[s], 0ull, (1ull << 32) | (u64)(id + 1u));
                    if (got == 0ull) break;
                    if ((uint32_t)got == id + 1u) { atomicAdd(&slot[s], 1ull << 32); break; }
                }
                s = (s + 1) & HMASK;
            }
        }
    }
    __syncthreads();

    // --- Phase B: local top-5 over 8 slots/thread (keys unique) ---
    u64 loc[K_WIN] = {0ull, 0ull, 0ull, 0ull, 0ull};
    for (int i = tid; i < HSZ; i += TB1) {
        u64 cur = slot[i];
        if (cur) {
            uint32_t id = (uint32_t)cur - 1u;
            u64 key = (cur & 0xFFFFFFFF00000000ull) | (u64)(0xFFFFFFFFu - id);
            if (key > loc[K_WIN - 1]) {
                loc[K_WIN - 1] = key;
                for (int j = K_WIN - 1; j > 0 && loc[j] > loc[j - 1]; --j) {
                    u64 t = loc[j]; loc[j] = loc[j - 1]; loc[j - 1] = t;
                }
            }
        }
    }

    // --- Phase C: block top-5 reduce ---
    int nz = 0;
    for (int it = 0; it < K_WIN; ++it) {
        u64 k = loc[0];
        for (int off = 32; off; off >>= 1) k = u64max(k, __shfl_xor(k, off));
        if (lane == 0) sWave[wid] = k;
        __syncthreads();
        if (tid == 0) {
            u64 w = sWave[0];
            for (int i = 1; i < TB1 / 64; ++i) w = u64max(w, sWave[i]);
            sWin = w;
            sWinners[it] = w ? (0xFFFFFFFFu - (uint32_t)(w & 0xFFFFFFFFull))
                             : 0xFFFFFFFFu;
        }
        __syncthreads();
        u64 w = sWin;
        if (w && loc[0] == w) {  // unique key -> exactly one holder retires it
            for (int j = 0; j < K_WIN - 1; ++j) loc[j] = loc[j + 1];
            loc[K_WIN - 1] = 0ull;
        }
        if (w) ++nz;
        __syncthreads();  // sWave/sWin reuse hazard
    }

    // --- Phase D: degenerate (<5 distinct) fallback -- dead for bench ---
    if (tid == 0 && nz < K_WIN) {
        // remaining picks = lowest-index zero-count entries (lax.top_k order)
        int p = nz;
        for (uint32_t v = 0; p < K_WIN && v < (uint32_t)V; ++v) {
            uint32_t s = hashf(v) & HMASK;
            uint32_t c = 0u;
            for (;;) {
                u64 cur = slot[s];
                uint32_t lo = (uint32_t)cur;
                if (lo == 0u) break;
                if (lo == v + 1u) { c = (uint32_t)(cur >> 32); break; }
                s = (s + 1) & HMASK;
            }
            if (c == 0u) sWinners[p++] = v;
        }
    }
    __syncthreads();

    // --- Phase E: publish winners + write the five 1.5s ---
    if (tid < K_WIN) {
        uint32_t idx = sWinners[tid];
        wsw[tid] = idx;
        if (idx < (uint32_t)V) gains[idx] = 1.5f;
    }
}

__global__ __launch_bounds__(TB2) void fill_kernel(const int* __restrict__ ids,
                                                   const uint32_t* __restrict__ wsw,
                                                   float* __restrict__ gains,
                                                   int L, int V) {
    __shared__ uint32_t flag[SLICE2];
    __shared__ uint32_t win[K_WIN];

    const int tid = threadIdx.x;
    const int base = blockIdx.x * SLICE2;

    if (tid < K_WIN) win[tid] = wsw[tid];   // K1 stream-ordered before us
    flag[tid] = 0u;                          // TB2 == SLICE2
    __syncthreads();

    // scan full id list; flag ids inside [base, base+SLICE2)
    for (int i0 = tid * 8; i0 < L; i0 += TB2 * 8) {
        #pragma unroll
        for (int j = 0; j < 8; j += 4) {
            int i = i0 + j;
            if (i + 3 < L) {
                int4 w = *reinterpret_cast<const int4*>(ids + i);
                uint32_t d;
                d = (uint32_t)(w.x - base); if (d < SLICE2) flag[d] = 1u;
                d = (uint32_t)(w.y - base); if (d < SLICE2) flag[d] = 1u;
                d = (uint32_t)(w.z - base); if (d < SLICE2) flag[d] = 1u;
                d = (uint32_t)(w.w - base); if (d < SLICE2) flag[d] = 1u;
            } else {
                for (; i < L; ++i) {
                    uint32_t d = (uint32_t)(ids[i] - base);
                    if (d < SLICE2) flag[d] = 1u;
                }
            }
        }
    }
    __syncthreads();

    const int v = base + tid;
    if (v < V) {
        bool isw = false;
        #pragma unroll
        for (int k = 0; k < K_WIN; ++k) isw |= (win[k] == (uint32_t)v);
        if (!isw) gains[v] = flag[tid] ? 0.6f : 1.0f;  // winners keep K1's 1.5
    }
}

extern "C" void kernel_launch(void* const* d_in, const int* in_sizes, int n_in,
                              void* d_out, int out_size, void* d_ws, size_t ws_size,
                              hipStream_t stream) {
    const int* ids = (const int*)d_in[0];   // token_ids (int32 per harness)
    const int L = in_sizes[0];              // 4096
    const int V = out_size;                 // 131072
    float* gains = (float*)d_out;
    uint32_t* wsw = (uint32_t*)d_ws;        // 5 winner indices

    topk_kernel<<<1, TB1, 0, stream>>>(ids, gains, wsw, L, V);
    const int nblk2 = (V + SLICE2 - 1) / SLICE2;  // 256
    fill_kernel<<<nblk2, TB2, 0, stream>>>(ids, wsw, gains, L, V);
}